// Round 4
// baseline (206811.938 us; speedup 1.0000x reference)
//
#include <hip/hip_runtime.h>
#include <math.h>

#define FIN   32
#define HH    512
#define G4    2048
#define BNE   64
#define OUTD  8
#define SEQL  128
#define LOOK  32
#define TOT   (SEQL + LOOK)
#define GS    32              // samples per 4-WG group
#define NTHR  1024
#define NWG   256

// ---- workspace layout (float indices) ----
#define ST_SZ   (64 * HH * GS)                 // one state array, all 64 groups
#define WS_ST   1024                            // 4KB of group counters first
#define WS_H0D  (WS_ST + 4 * ST_SZ)
#define WS_H1D  (WS_H0D + ST_SZ)
#define WS_TR   (WS_H1D + ST_SZ)                // trits [64][2][64][32]
#define WS_SOUT (WS_TR + 64 * 2 * BNE * GS)     // sout  [64][32][8]

__device__ __forceinline__ float sigf(float v) { return 1.0f / (1.0f + expf(-v)); }

// 4-WG group barrier: monotonic counter, device-scope
__device__ __forceinline__ void gbar(int* cnt, int target) {
  __syncthreads();
  if (threadIdx.x == 0) {
    __hip_atomic_fetch_add(cnt, 1, __ATOMIC_ACQ_REL, __HIP_MEMORY_SCOPE_AGENT);
    while (__hip_atomic_load(cnt, __ATOMIC_ACQUIRE, __HIP_MEMORY_SCOPE_AGENT) < target)
      __builtin_amdgcn_s_sleep(4);
  }
  __syncthreads();
  __threadfence();   // acquire: invalidate L1 so peers' writes are visible
}

// acc[si] (float2) += hs * w  for 8 samples
#define MACQ(HA, HB)                                            \
  { a[0].x = fmaf(w.x, HA.x, a[0].x); a[0].y = fmaf(w.y, HA.x, a[0].y); \
    a[1].x = fmaf(w.x, HA.y, a[1].x); a[1].y = fmaf(w.y, HA.y, a[1].y); \
    a[2].x = fmaf(w.x, HA.z, a[2].x); a[2].y = fmaf(w.y, HA.z, a[2].y); \
    a[3].x = fmaf(w.x, HA.w, a[3].x); a[3].y = fmaf(w.y, HA.w, a[3].y); \
    a[4].x = fmaf(w.x, HB.x, a[4].x); a[4].y = fmaf(w.y, HB.x, a[4].y); \
    a[5].x = fmaf(w.x, HB.y, a[5].x); a[5].y = fmaf(w.y, HB.y, a[5].y); \
    a[6].x = fmaf(w.x, HB.z, a[6].x); a[6].y = fmaf(w.y, HB.z, a[6].y); \
    a[7].x = fmaf(w.x, HB.w, a[7].x); a[7].y = fmaf(w.y, HB.w, a[7].y); }

__global__ __launch_bounds__(NTHR)
void fused_rnn(const float* __restrict__ x,
               const float* __restrict__ Wih0, const float* __restrict__ Whh0,
               const float* __restrict__ bih0, const float* __restrict__ bhh0,
               const float* __restrict__ Wih1, const float* __restrict__ Whh1,
               const float* __restrict__ bih1, const float* __restrict__ bhh1,
               const float* __restrict__ We,   const float* __restrict__ be,
               const float* __restrict__ Wd,   const float* __restrict__ bd,
               const float* __restrict__ Wf,   const float* __restrict__ bf,
               float* __restrict__ out, float* __restrict__ ws)
{
  __shared__ float gbuf[GS][HH];          // 64KB: gate quarter [sample][local col]
  __shared__ float tq[2][BNE][GS];        // 16KB: trits (P2); sxT overlay (P3)
  __shared__ float cd[2][128][GS + 1];    // 33KB: decoded c quarters (padded)

  const int t   = threadIdx.x;
  const int bid = blockIdx.x;
  const int G   = bid & 63;               // group
  const int Q   = bid >> 6;               // quarter 0..3
  const int S0  = G * GS;                 // first global sample of group
  const int UQ  = Q * 128;                // unit-quarter base

  int*   cnt = (int*)ws + G * 16;
  float* h0c = ws + WS_ST + 0 * ST_SZ + G * (HH * GS);
  float* c0c = ws + WS_ST + 1 * ST_SZ + G * (HH * GS);
  float* h1c = ws + WS_ST + 2 * ST_SZ + G * (HH * GS);
  float* c1c = ws + WS_ST + 3 * ST_SZ + G * (HH * GS);
  float* h0d = ws + WS_H0D + G * (HH * GS);
  float* h1d = ws + WS_H1D + G * (HH * GS);
  float* trg = ws + WS_TR  + G * (2 * BNE * GS);
  float* sog = ws + WS_SOUT + G * (GS * OUTD);

  // ---- matmul thread mapping: wave (p, v); lanes w own col pair ----
  const int u = t & 255, v = t >> 8;      // v: sample block (8 samples)
  const int p = u >> 6, wl = u & 63;      // gate panel, col-pair lane
  const int cg = p * HH + UQ + 2 * wl;    // global gate column (even)
  const float2 bb0 = make_float2(bih0[cg] + bhh0[cg], bih0[cg + 1] + bhh0[cg + 1]);
  const float2 bb1 = make_float2(bih1[cg] + bhh1[cg], bih1[cg + 1] + bhh1[cg + 1]);

  // ---- decode mapping ----
  const int cl = t & 255, sg2 = t >> 8;   // col-local, sample block
  const int dcol = (cl < 128) ? (UQ + cl) : (HH + UQ + (cl - 128));
  const float bdv = bd[dcol];

  // ---- encoder mapping: WG handles group-samples [8Q, 8Q+8) ----
  const int ae = t >> 9, se = (t >> 6) & 7, n = t & 63;
  const int sE = 8 * Q + se;

  // ---- elementwise mapping ----
  const int ul = t & 127, sq8 = t >> 7;   // unit-local, sample block of 4

  const double Athr = 0.5493061443340549; // atanh(0.5)

  int bar = 0;

  for (int step = 0; step < TOT; ++step) {
    // ============ P1: AE encoders (fp64, full-k chains, 8 samples) ============
    {
      const float* Sh = ae ? h1c : h0c;
      const float* Sc = ae ? c1c : c0c;
      double a0 = (double)be[n];
      const float* weh = We + n;
#pragma unroll 4
      for (int k = 0; k < HH; k++)
        a0 = fma((double)Sh[k * GS + sE], (double)weh[(size_t)k * BNE], a0);
      const float* wec = We + (size_t)HH * BNE + n;
#pragma unroll 4
      for (int k = 0; k < HH; k++)
        a0 = fma((double)Sc[k * GS + sE], (double)wec[(size_t)k * BNE], a0);
      trg[ae * (BNE * GS) + n * GS + sE] =
          (a0 > Athr) ? 1.f : ((a0 < -Athr) ? -1.f : 0.f);
    }
    gbar(cnt, 4 * (++bar));

    // ============ P2: AE decode (column quarter, both AEs) ============
    {
      for (int i = t; i < 2 * BNE * GS; i += NTHR) (&tq[0][0][0])[i] = trg[i];
      __syncthreads();
      float ac0[8], ac1[8];
#pragma unroll
      for (int s = 0; s < 8; s++) { ac0[s] = bdv; ac1[s] = bdv; }
      const float* wd = Wd + dcol;
#pragma unroll 2
      for (int j = 0; j < BNE; j++) {
        const float wv = wd[(size_t)j * (2 * HH)];
        const float4 qA0 = *(const float4*)&tq[0][j][8 * sg2];
        const float4 qB0 = *(const float4*)&tq[0][j][8 * sg2 + 4];
        const float4 qA1 = *(const float4*)&tq[1][j][8 * sg2];
        const float4 qB1 = *(const float4*)&tq[1][j][8 * sg2 + 4];
        ac0[0] = fmaf(qA0.x, wv, ac0[0]); ac0[1] = fmaf(qA0.y, wv, ac0[1]);
        ac0[2] = fmaf(qA0.z, wv, ac0[2]); ac0[3] = fmaf(qA0.w, wv, ac0[3]);
        ac0[4] = fmaf(qB0.x, wv, ac0[4]); ac0[5] = fmaf(qB0.y, wv, ac0[5]);
        ac0[6] = fmaf(qB0.z, wv, ac0[6]); ac0[7] = fmaf(qB0.w, wv, ac0[7]);
        ac1[0] = fmaf(qA1.x, wv, ac1[0]); ac1[1] = fmaf(qA1.y, wv, ac1[1]);
        ac1[2] = fmaf(qA1.z, wv, ac1[2]); ac1[3] = fmaf(qA1.w, wv, ac1[3]);
        ac1[4] = fmaf(qB1.x, wv, ac1[4]); ac1[5] = fmaf(qB1.y, wv, ac1[5]);
        ac1[6] = fmaf(qB1.z, wv, ac1[6]); ac1[7] = fmaf(qB1.w, wv, ac1[7]);
      }
      if (cl < 128) {
        const int row = (UQ + cl) * GS + 8 * sg2;
#pragma unroll
        for (int s = 0; s < 8; s++) { h0d[row + s] = ac0[s]; h1d[row + s] = ac1[s]; }
      } else {
#pragma unroll
        for (int s = 0; s < 8; s++) {
          cd[0][cl - 128][8 * sg2 + s] = ac0[s];
          cd[1][cl - 128][8 * sg2 + s] = ac1[s];
        }
      }
    }
    gbar(cnt, 4 * (++bar));

    // ============ P3: layer-0 LSTM (column quarter) ============
    {
      float* sxT = &tq[0][0][0];           // [32 feat][32 samp] overlay
      { int s = t >> 5, f = t & 31;
        float xv;
        if (step >= SEQL && f < OUTD) xv = sog[s * OUTD + f];
        else xv = x[((size_t)(S0 + s) * TOT + step) * FIN + f];
        sxT[f * GS + s] = xv; }
      __syncthreads();

      float2 a[8];
#pragma unroll
      for (int s = 0; s < 8; s++) a[s] = bb0;
      const float2* wx = (const float2*)(Wih0 + cg);
#pragma unroll 4
      for (int k = 0; k < FIN; k++) {
        const float2 w  = wx[(size_t)k * (G4 / 2)];
        const float4 hA = *(const float4*)&sxT[k * GS + 8 * v];
        const float4 hB = *(const float4*)&sxT[k * GS + 8 * v + 4];
        MACQ(hA, hB);
      }
      const float2* wh = (const float2*)(Whh0 + cg);
#pragma unroll 8
      for (int k = 0; k < HH; k++) {
        const float2 w  = wh[(size_t)k * (G4 / 2)];
        const float4 hA = *(const float4*)&h0d[k * GS + 8 * v];
        const float4 hB = *(const float4*)&h0d[k * GS + 8 * v + 4];
        MACQ(hA, hB);
      }
      __syncthreads();   // sxT reads done before gbuf (tq untouched; safe) — order gates
#pragma unroll
      for (int s = 0; s < 8; s++)
        *(float2*)&gbuf[8 * v + s][p * 128 + 2 * wl] = a[s];
      __syncthreads();
      // elementwise: 128 units x 32 samples
#pragma unroll
      for (int i = 0; i < 4; i++) {
        const int s = sq8 * 4 + i;
        const float ig = sigf(gbuf[s][ul]);
        const float fg = sigf(gbuf[s][128 + ul]);
        const float gt = tanhf(gbuf[s][256 + ul]);
        const float og = sigf(gbuf[s][384 + ul]);
        const float c2 = fmaf(fg, cd[0][ul][s], ig * gt);
        h0c[(UQ + ul) * GS + s] = og * tanhf(c2);
        c0c[(UQ + ul) * GS + s] = c2;
      }
    }
    gbar(cnt, 4 * (++bar));

    // ============ P4: layer-1 LSTM (column quarter) ============
    {
      float2 a[8];
#pragma unroll
      for (int s = 0; s < 8; s++) a[s] = bb1;
      const float2* wx = (const float2*)(Wih1 + cg);
#pragma unroll 8
      for (int k = 0; k < HH; k++) {
        const float2 w  = wx[(size_t)k * (G4 / 2)];
        const float4 hA = *(const float4*)&h0c[k * GS + 8 * v];
        const float4 hB = *(const float4*)&h0c[k * GS + 8 * v + 4];
        MACQ(hA, hB);
      }
      const float2* wh = (const float2*)(Whh1 + cg);
#pragma unroll 8
      for (int k = 0; k < HH; k++) {
        const float2 w  = wh[(size_t)k * (G4 / 2)];
        const float4 hA = *(const float4*)&h1d[k * GS + 8 * v];
        const float4 hB = *(const float4*)&h1d[k * GS + 8 * v + 4];
        MACQ(hA, hB);
      }
      __syncthreads();
#pragma unroll
      for (int s = 0; s < 8; s++)
        *(float2*)&gbuf[8 * v + s][p * 128 + 2 * wl] = a[s];
      __syncthreads();
#pragma unroll
      for (int i = 0; i < 4; i++) {
        const int s = sq8 * 4 + i;
        const float ig = sigf(gbuf[s][ul]);
        const float fg = sigf(gbuf[s][128 + ul]);
        const float gt = tanhf(gbuf[s][256 + ul]);
        const float og = sigf(gbuf[s][384 + ul]);
        const float c2 = fmaf(fg, cd[1][ul][s], ig * gt);
        h1c[(UQ + ul) * GS + s] = og * tanhf(c2);
        c1c[(UQ + ul) * GS + s] = c2;
      }
    }
    gbar(cnt, 4 * (++bar));

    // ============ P5: final dense (WG's own 8 samples) ============
    if (step >= SEQL - 1) {
      if (t < 8 * OUTD) {
        const int s8 = t >> 3, o = t & 7;
        const int sl = 8 * Q + s8;
        float acc = bf[o];
#pragma unroll 4
        for (int k = 0; k < HH; k++)
          acc = fmaf(h1c[k * GS + sl], Wf[k * OUTD + o], acc);
        sog[sl * OUTD + o] = acc;
        const int slot = step - (SEQL - 1);
        out[((size_t)(S0 + sl) * (1 + LOOK) + slot) * OUTD + o] = acc;
      }
    }
  }
}

extern "C" void kernel_launch(void* const* d_in, const int* in_sizes, int n_in,
                              void* d_out, int out_size, void* d_ws, size_t ws_size,
                              hipStream_t stream) {
  const float* x    = (const float*)d_in[0];
  const float* Wih0 = (const float*)d_in[1];
  const float* Whh0 = (const float*)d_in[2];
  const float* bih0 = (const float*)d_in[3];
  const float* bhh0 = (const float*)d_in[4];
  const float* Wih1 = (const float*)d_in[5];
  const float* Whh1 = (const float*)d_in[6];
  const float* bih1 = (const float*)d_in[7];
  const float* bhh1 = (const float*)d_in[8];
  const float* We   = (const float*)d_in[9];
  const float* be   = (const float*)d_in[10];
  const float* Wd   = (const float*)d_in[11];
  const float* bd   = (const float*)d_in[12];
  const float* Wf   = (const float*)d_in[13];
  const float* bf   = (const float*)d_in[14];

  // zero group counters + initial states (h0,c0,h1,c1) every launch
  hipMemsetAsync(d_ws, 0, (size_t)(WS_ST + 4 * ST_SZ) * sizeof(float), stream);

  fused_rnn<<<NWG, NTHR, 0, stream>>>(x, Wih0, Whh0, bih0, bhh0,
                                      Wih1, Whh1, bih1, bhh1,
                                      We, be, Wd, bd, Wf, bf,
                                      (float*)d_out, (float*)d_ws);
}

// Round 6
// 92003.027 us; speedup vs baseline: 2.2479x; 2.2479x over previous
//
#include <hip/hip_runtime.h>
#include <math.h>

#define NB    2048
#define FIN   32
#define HH    512
#define G4    2048           // 4*H
#define BNE   64
#define OUTD  8
#define SEQL  128
#define LOOK  32
#define TOT   (SEQL + LOOK)
#define TB    8              // samples per workgroup
#define NTHR  512

__device__ __forceinline__ float sigf(float v) { return 1.0f / (1.0f + expf(-v)); }

// One k-slice: gate accum A[s] (float2 over unit-pair) += w * state[s]
#define GMAC4(A, W)                                                     \
  { A[0].x = fmaf((W).x, hv.x, A[0].x); A[0].y = fmaf((W).y, hv.x, A[0].y); \
    A[1].x = fmaf((W).x, hv.y, A[1].x); A[1].y = fmaf((W).y, hv.y, A[1].y); \
    A[2].x = fmaf((W).x, hv.z, A[2].x); A[2].y = fmaf((W).y, hv.z, A[2].y); \
    A[3].x = fmaf((W).x, hv.w, A[3].x); A[3].y = fmaf((W).y, hv.w, A[3].y); }

__global__ __launch_bounds__(NTHR)
void fused_rnn(const float* __restrict__ x,
               const float* __restrict__ Wih0, const float* __restrict__ Whh0,
               const float* __restrict__ bih0, const float* __restrict__ bhh0,
               const float* __restrict__ Wih1, const float* __restrict__ Whh1,
               const float* __restrict__ bih1, const float* __restrict__ bhh1,
               const float* __restrict__ We,   const float* __restrict__ be,
               const float* __restrict__ Wd,   const float* __restrict__ bd,
               const float* __restrict__ Wf,   const float* __restrict__ bf,
               float* __restrict__ out)
{
  // states [unit][sample]: fixed-k access is a wave-uniform b128 broadcast
  __shared__ float sh0[HH][TB], sc0[HH][TB], sh1[HH][TB], sc1[HH][TB];  // 64 KB
  __shared__ float tq[2][BNE][TB];   // trits as float, 4 KB
  __shared__ float sx[FIN][TB];      // staged x_t, 1 KB
  __shared__ float sout[TB][OUTD];   // dense output (AR feedback)

  const int t  = threadIdx.x;          // 0..511
  const int b0 = blockIdx.x * TB;

  for (int i = t; i < HH * TB; i += NTHR) {
    (&sh0[0][0])[i] = 0.f; (&sc0[0][0])[i] = 0.f;
    (&sh1[0][0])[i] = 0.f; (&sc1[0][0])[i] = 0.f;
  }

  // ---- matmul mapping: thread owns units {2q, 2q+1} (all 4 gates), samples [4*sh,4*sh+4) ----
  const int q  = t & 255;              // unit-pair index
  const int sh = t >> 8;               // sample half
  const int s4 = 4 * sh;
  const int u0 = 2 * q;                // first owned unit
  float2 bg0[4], bg1[4];
#pragma unroll
  for (int m = 0; m < 4; m++) {
    const int c = m * HH + u0;
    bg0[m] = make_float2(bih0[c] + bhh0[c], bih0[c + 1] + bhh0[c + 1]);
    bg1[m] = make_float2(bih1[c] + bhh1[c], bih1[c + 1] + bhh1[c + 1]);
  }

  // ---- encoder mapping: (ae, n, sample-pair) ----
  const int ae = t >> 8, n = t & 63, sp = (t >> 6) & 3;

  // ---- decoder mapping: cols {2t, 2t+1} of Wd (h-part if t<256, c-part else) ----
  const float bdx = bd[2 * t], bdy = bd[2 * t + 1];

  const double Athr = 0.5493061443340549;  // atanh(0.5)

  for (int step = 0; step < TOT; ++step) {
    __syncthreads();

    // ================= A: AE encoders (fp64, exact chain order, 2 samples/thread) ====
    {
      const float* Sh = ae ? &sh1[0][0] : &sh0[0][0];
      const float* Sc = ae ? &sc1[0][0] : &sc0[0][0];
      double a0 = (double)be[n], a1 = a0;
      const float* weh = We + n;
#pragma unroll 4
      for (int k = 0; k < HH; k++) {
        const float2 zz = *(const float2*)&Sh[k * TB + 2 * sp];
        const double wv = (double)weh[(size_t)k * BNE];
        a0 = fma((double)zz.x, wv, a0);
        a1 = fma((double)zz.y, wv, a1);
      }
      const float* wec = We + (size_t)HH * BNE + n;
#pragma unroll 4
      for (int k = 0; k < HH; k++) {
        const float2 zz = *(const float2*)&Sc[k * TB + 2 * sp];
        const double wv = (double)wec[(size_t)k * BNE];
        a0 = fma((double)zz.x, wv, a0);
        a1 = fma((double)zz.y, wv, a1);
      }
      tq[ae][n][2 * sp]     = (a0 > Athr) ? 1.f : ((a0 < -Athr) ? -1.f : 0.f);
      tq[ae][n][2 * sp + 1] = (a1 > Athr) ? 1.f : ((a1 < -Athr) ? -1.f : 0.f);
    }
    __syncthreads();

    // ================= B: AE decode (col-pair, 8 samples, both AEs) + stage x_t ======
    {
      float2 d0[TB], d1[TB];
#pragma unroll
      for (int s = 0; s < TB; s++) { d0[s] = make_float2(bdx, bdy); d1[s] = d0[s]; }
      const float* wd = Wd + 2 * t;
#pragma unroll 2
      for (int j = 0; j < BNE; j++) {
        const float2 w = *(const float2*)&wd[(size_t)j * (2 * HH)];
        const float4 qA0 = *(const float4*)&tq[0][j][0];
        const float4 qB0 = *(const float4*)&tq[0][j][4];
        const float4 qA1 = *(const float4*)&tq[1][j][0];
        const float4 qB1 = *(const float4*)&tq[1][j][4];
        d0[0].x = fmaf(qA0.x, w.x, d0[0].x); d0[0].y = fmaf(qA0.x, w.y, d0[0].y);
        d0[1].x = fmaf(qA0.y, w.x, d0[1].x); d0[1].y = fmaf(qA0.y, w.y, d0[1].y);
        d0[2].x = fmaf(qA0.z, w.x, d0[2].x); d0[2].y = fmaf(qA0.z, w.y, d0[2].y);
        d0[3].x = fmaf(qA0.w, w.x, d0[3].x); d0[3].y = fmaf(qA0.w, w.y, d0[3].y);
        d0[4].x = fmaf(qB0.x, w.x, d0[4].x); d0[4].y = fmaf(qB0.x, w.y, d0[4].y);
        d0[5].x = fmaf(qB0.y, w.x, d0[5].x); d0[5].y = fmaf(qB0.y, w.y, d0[5].y);
        d0[6].x = fmaf(qB0.z, w.x, d0[6].x); d0[6].y = fmaf(qB0.z, w.y, d0[6].y);
        d0[7].x = fmaf(qB0.w, w.x, d0[7].x); d0[7].y = fmaf(qB0.w, w.y, d0[7].y);
        d1[0].x = fmaf(qA1.x, w.x, d1[0].x); d1[0].y = fmaf(qA1.x, w.y, d1[0].y);
        d1[1].x = fmaf(qA1.y, w.x, d1[1].x); d1[1].y = fmaf(qA1.y, w.y, d1[1].y);
        d1[2].x = fmaf(qA1.z, w.x, d1[2].x); d1[2].y = fmaf(qA1.z, w.y, d1[2].y);
        d1[3].x = fmaf(qA1.w, w.x, d1[3].x); d1[3].y = fmaf(qA1.w, w.y, d1[3].y);
        d1[4].x = fmaf(qB1.x, w.x, d1[4].x); d1[4].y = fmaf(qB1.x, w.y, d1[4].y);
        d1[5].x = fmaf(qB1.y, w.x, d1[5].x); d1[5].y = fmaf(qB1.y, w.y, d1[5].y);
        d1[6].x = fmaf(qB1.z, w.x, d1[6].x); d1[6].y = fmaf(qB1.z, w.y, d1[6].y);
        d1[7].x = fmaf(qB1.w, w.x, d1[7].x); d1[7].y = fmaf(qB1.w, w.y, d1[7].y);
      }
      if (t < 256) {             // h-units 2t, 2t+1
        const int u = 2 * t;
        *(float4*)&sh0[u][0]     = make_float4(d0[0].x, d0[1].x, d0[2].x, d0[3].x);
        *(float4*)&sh0[u][4]     = make_float4(d0[4].x, d0[5].x, d0[6].x, d0[7].x);
        *(float4*)&sh0[u + 1][0] = make_float4(d0[0].y, d0[1].y, d0[2].y, d0[3].y);
        *(float4*)&sh0[u + 1][4] = make_float4(d0[4].y, d0[5].y, d0[6].y, d0[7].y);
        *(float4*)&sh1[u][0]     = make_float4(d1[0].x, d1[1].x, d1[2].x, d1[3].x);
        *(float4*)&sh1[u][4]     = make_float4(d1[4].x, d1[5].x, d1[6].x, d1[7].x);
        *(float4*)&sh1[u + 1][0] = make_float4(d1[0].y, d1[1].y, d1[2].y, d1[3].y);
        *(float4*)&sh1[u + 1][4] = make_float4(d1[4].y, d1[5].y, d1[6].y, d1[7].y);
      } else {                   // c-units 2t-HH, 2t-HH+1  (cols 2t of Wd are c-part)
        const int u = 2 * t - HH;
        *(float4*)&sc0[u][0]     = make_float4(d0[0].x, d0[1].x, d0[2].x, d0[3].x);
        *(float4*)&sc0[u][4]     = make_float4(d0[4].x, d0[5].x, d0[6].x, d0[7].x);
        *(float4*)&sc0[u + 1][0] = make_float4(d0[0].y, d0[1].y, d0[2].y, d0[3].y);
        *(float4*)&sc0[u + 1][4] = make_float4(d0[4].y, d0[5].y, d0[6].y, d0[7].y);
        *(float4*)&sc1[u][0]     = make_float4(d1[0].x, d1[1].x, d1[2].x, d1[3].x);
        *(float4*)&sc1[u][4]     = make_float4(d1[4].x, d1[5].x, d1[6].x, d1[7].x);
        *(float4*)&sc1[u + 1][0] = make_float4(d1[0].y, d1[1].y, d1[2].y, d1[3].y);
        *(float4*)&sc1[u + 1][4] = make_float4(d1[4].y, d1[5].y, d1[6].y, d1[7].y);
      }
      if (t < FIN * TB) {        // stage x_t (with AR feedback)
        int s = t >> 5, f = t & 31;
        float xv;
        if (step >= SEQL && f < OUTD) xv = sout[s][f];
        else xv = x[((size_t)(b0 + s) * TOT + step) * FIN + f];
        sx[f][s] = xv;
      }
    }
    __syncthreads();

    // ================= C: layer-0 LSTM =================
    {
      float2 gI[4], gF[4], gG[4], gO[4];
#pragma unroll
      for (int i = 0; i < 4; i++) { gI[i] = bg0[0]; gF[i] = bg0[1]; gG[i] = bg0[2]; gO[i] = bg0[3]; }
      {
        const float* row = Wih0 + u0;
#pragma unroll 4
        for (int k = 0; k < FIN; k++, row += G4) {
          const float2 wI = *(const float2*)(row);
          const float2 wF = *(const float2*)(row + HH);
          const float2 wG = *(const float2*)(row + 2 * HH);
          const float2 wO = *(const float2*)(row + 3 * HH);
          const float4 hv = *(const float4*)&sx[k][s4];
          GMAC4(gI, wI); GMAC4(gF, wF); GMAC4(gG, wG); GMAC4(gO, wO);
        }
      }
      {
        const float* row = Whh0 + u0;
#pragma unroll 8
        for (int k = 0; k < HH; k++, row += G4) {
          const float2 wI = *(const float2*)(row);
          const float2 wF = *(const float2*)(row + HH);
          const float2 wG = *(const float2*)(row + 2 * HH);
          const float2 wO = *(const float2*)(row + 3 * HH);
          const float4 hv = *(const float4*)&sh0[k][s4];
          GMAC4(gI, wI); GMAC4(gF, wF); GMAC4(gG, wG); GMAC4(gO, wO);
        }
      }
      const float4 cA = *(const float4*)&sc0[u0][s4];
      const float4 cB = *(const float4*)&sc0[u0 + 1][s4];
      const float coldA[4] = { cA.x, cA.y, cA.z, cA.w };
      const float coldB[4] = { cB.x, cB.y, cB.z, cB.w };
      float4 hnA, hnB, cnA, cnB;
      float* hA = (float*)&hnA; float* hB = (float*)&hnB;
      float* cnAp = (float*)&cnA; float* cnBp = (float*)&cnB;
#pragma unroll
      for (int i = 0; i < 4; i++) {
        float ig = sigf(gI[i].x), fg = sigf(gF[i].x);
        float gt = tanhf(gG[i].x), og = sigf(gO[i].x);
        float c2 = fmaf(fg, coldA[i], ig * gt);
        cnAp[i] = c2; hA[i] = og * tanhf(c2);
        ig = sigf(gI[i].y); fg = sigf(gF[i].y);
        gt = tanhf(gG[i].y); og = sigf(gO[i].y);
        c2 = fmaf(fg, coldB[i], ig * gt);
        cnBp[i] = c2; hB[i] = og * tanhf(c2);
      }
      __syncthreads();   // all K-loop reads of decoded sh0 done before overwrite
      *(float4*)&sh0[u0][s4]     = hnA;
      *(float4*)&sh0[u0 + 1][s4] = hnB;
      *(float4*)&sc0[u0][s4]     = cnA;
      *(float4*)&sc0[u0 + 1][s4] = cnB;
    }
    __syncthreads();

    // ================= D: layer-1 LSTM =================
    {
      float2 gI[4], gF[4], gG[4], gO[4];
#pragma unroll
      for (int i = 0; i < 4; i++) { gI[i] = bg1[0]; gF[i] = bg1[1]; gG[i] = bg1[2]; gO[i] = bg1[3]; }
      {
        const float* row = Wih1 + u0;
#pragma unroll 8
        for (int k = 0; k < HH; k++, row += G4) {
          const float2 wI = *(const float2*)(row);
          const float2 wF = *(const float2*)(row + HH);
          const float2 wG = *(const float2*)(row + 2 * HH);
          const float2 wO = *(const float2*)(row + 3 * HH);
          const float4 hv = *(const float4*)&sh0[k][s4];   // new h0
          GMAC4(gI, wI); GMAC4(gF, wF); GMAC4(gG, wG); GMAC4(gO, wO);
        }
      }
      {
        const float* row = Whh1 + u0;
#pragma unroll 8
        for (int k = 0; k < HH; k++, row += G4) {
          const float2 wI = *(const float2*)(row);
          const float2 wF = *(const float2*)(row + HH);
          const float2 wG = *(const float2*)(row + 2 * HH);
          const float2 wO = *(const float2*)(row + 3 * HH);
          const float4 hv = *(const float4*)&sh1[k][s4];   // decoded h1
          GMAC4(gI, wI); GMAC4(gF, wF); GMAC4(gG, wG); GMAC4(gO, wO);
        }
      }
      const float4 cA = *(const float4*)&sc1[u0][s4];
      const float4 cB = *(const float4*)&sc1[u0 + 1][s4];
      const float coldA[4] = { cA.x, cA.y, cA.z, cA.w };
      const float coldB[4] = { cB.x, cB.y, cB.z, cB.w };
      float4 hnA, hnB, cnA, cnB;
      float* hA = (float*)&hnA; float* hB = (float*)&hnB;
      float* cnAp = (float*)&cnA; float* cnBp = (float*)&cnB;
#pragma unroll
      for (int i = 0; i < 4; i++) {
        float ig = sigf(gI[i].x), fg = sigf(gF[i].x);
        float gt = tanhf(gG[i].x), og = sigf(gO[i].x);
        float c2 = fmaf(fg, coldA[i], ig * gt);
        cnAp[i] = c2; hA[i] = og * tanhf(c2);
        ig = sigf(gI[i].y); fg = sigf(gF[i].y);
        gt = tanhf(gG[i].y); og = sigf(gO[i].y);
        c2 = fmaf(fg, coldB[i], ig * gt);
        cnBp[i] = c2; hB[i] = og * tanhf(c2);
      }
      __syncthreads();   // all K-loop reads of sh1 done before overwrite
      *(float4*)&sh1[u0][s4]     = hnA;
      *(float4*)&sh1[u0 + 1][s4] = hnB;
      *(float4*)&sc1[u0][s4]     = cnA;
      *(float4*)&sc1[u0 + 1][s4] = cnB;
    }

    // ================= E: final dense =================
    if (step >= SEQL - 1) {
      __syncthreads();  // new sh1 visible
      if (t < TB * OUTD) {
        int s = t >> 3, o = t & 7;
        float a = bf[o];
#pragma unroll 4
        for (int k = 0; k < HH; k++) a = fmaf(sh1[k][s], Wf[k * OUTD + o], a);
        sout[s][o] = a;
        int slot = step - (SEQL - 1);
        out[((size_t)(b0 + s) * (1 + LOOK) + slot) * OUTD + o] = a;
      }
    }
  }
}

extern "C" void kernel_launch(void* const* d_in, const int* in_sizes, int n_in,
                              void* d_out, int out_size, void* d_ws, size_t ws_size,
                              hipStream_t stream) {
  const float* x    = (const float*)d_in[0];
  const float* Wih0 = (const float*)d_in[1];
  const float* Whh0 = (const float*)d_in[2];
  const float* bih0 = (const float*)d_in[3];
  const float* bhh0 = (const float*)d_in[4];
  const float* Wih1 = (const float*)d_in[5];
  const float* Whh1 = (const float*)d_in[6];
  const float* bih1 = (const float*)d_in[7];
  const float* bhh1 = (const float*)d_in[8];
  const float* We   = (const float*)d_in[9];
  const float* be   = (const float*)d_in[10];
  const float* Wd   = (const float*)d_in[11];
  const float* bd   = (const float*)d_in[12];
  const float* Wf   = (const float*)d_in[13];
  const float* bf   = (const float*)d_in[14];

  fused_rnn<<<NB / TB, NTHR, 0, stream>>>(x, Wih0, Whh0, bih0, bhh0,
                                          Wih1, Whh1, bih1, bhh1,
                                          We, be, Wd, bd, Wf, bf,
                                          (float*)d_out);
}